// Round 10
// baseline (100.579 us; speedup 1.0000x reference)
//
#include <hip/hip_runtime.h>
#include <hip/hip_bf16.h>

// SpatialAttention: out[b,i,j] = softmax_j( sum_c w3[c] * tanh(x1[b,i,c] + x2[b,j,c]) )
// x1 = x@W1^T, x2 = x@W2^T.  B=4, N=1024, C=64.
//
// tanh(s) = 1 - 2/(exp2(K2*s)+1), K2 = 2*log2(e); exp2 factorizes:
// exp2(K2*(x1+x2)) = e1*e2, precomputed in proj (each clamped to 2^15).
// att = sum(w3) - 2 * sum_c w3[c] * rcp(fma(e1,e2,1)).
//
// R16: 8 nulls (R7-R15) varied VMEM pattern, LDS traffic, uniform path,
// prefetch depth, occupancy, full-rate instr count -- all ~0.  The ONE
// never-varied resource: rcp count (0.5/element, 134M lane-rcps on the
// narrow trans pipe; at ~8-16 lanes/cy/CU that is 13-27us issue-blocking =
// the unexplained half of attn's 40us).  Fix: 4-way reciprocal batching
// over the 4 i's of one (j,c):
//   P = (d1 d2)(d3 d4); r = rcp(P); rw = wc*r;
//   t_lo = p_hi*rw = wc/(d1 d2); t_hi = p_lo*rw;
//   accLo += pk_fma(dlo.yx, t_lo); accHi += pk_fma(dhi.yx, t_hi)
// Per 4 elements: 4 pk_fma + 6 mul + 1 rcp (was 10 slots + 2 rcp):
// full-rate +10%, rcp -50%.  d <= 1+2^30 -> P <= 2^120 < fp32 max (safe);
// added relative error ~3e-7 (negligible vs 1.5e-5 absmax).
// proj reverted to R13/R14 shape (R15's PROWS=4 quadrupled per-block
// W-staging for 1/4 the work -> net regression).  All else frozen.

#define BATCH 4
#define NN    1024
#define CC    64
#define TI    4              // rows i per attn block
#define BLK   256
#define PP    65             // padded pitch for transposed W in LDS
#define PROWS 16             // rows per proj block

typedef float v2f __attribute__((ext_vector_type(2)));

__device__ __forceinline__ float fast_exp2(float x) {
#if __has_builtin(__builtin_amdgcn_exp2f)
    return __builtin_amdgcn_exp2f(x);
#else
    return exp2f(x);
#endif
}
__device__ __forceinline__ float fast_rcp(float x) {
#if __has_builtin(__builtin_amdgcn_rcpf)
    return __builtin_amdgcn_rcpf(x);
#else
    return 1.0f / x;
#endif
}

// ---------------- Kernel 1: projections -> exp2 factors ---------------------
// grid 256 x 512 thr; block handles rows r0..r0+15; wave w does 2 rows.
// e1p: natural [b*n][c].  e2p: c-quad-major [b][c/4][n][4] (float4 per (cq,n)).
__global__ __launch_bounds__(512) void proj_kernel(
    const float* __restrict__ x, const float* __restrict__ W1,
    const float* __restrict__ W2, float* __restrict__ e1p,
    float* __restrict__ e2p) {
    __shared__ float w1t[CC * PP];        // [c][d] transposed, 16.25 KB
    __shared__ float w2t[CC * PP];
    __shared__ float xs[PROWS * CC];      // [r][c] straight, 4 KB

    const int tid = threadIdx.x;
    const int r0  = blockIdx.x * PROWS;
    {   // W: coalesced load + transpose into LDS
        const float4* __restrict__ W1v = (const float4*)W1;
        const float4* __restrict__ W2v = (const float4*)W2;
#pragma unroll
        for (int k = 0; k < 2; ++k) {
            const int fi = k * 512 + tid;      // float4 index in [0,1024)
            const int r  = fi >> 4;            // row d
            const int c4 = (fi & 15) * 4;      // col c base
            float4 a = W1v[fi], b = W2v[fi];
            w1t[(c4 + 0) * PP + r] = a.x; w1t[(c4 + 1) * PP + r] = a.y;
            w1t[(c4 + 2) * PP + r] = a.z; w1t[(c4 + 3) * PP + r] = a.w;
            w2t[(c4 + 0) * PP + r] = b.x; w2t[(c4 + 1) * PP + r] = b.y;
            w2t[(c4 + 2) * PP + r] = b.z; w2t[(c4 + 3) * PP + r] = b.w;
        }
        // x tile: coalesced, conflict-free
        const int rr = tid >> 6, c = tid & 63;
#pragma unroll
        for (int k = 0; k < 2; ++k) {
            const int r = k * 8 + rr;
            xs[r * CC + c] = x[(size_t)(r0 + r) * CC + c];
        }
    }
    __syncthreads();

    const int w    = tid >> 6;            // 0..7
    const int lane = tid & 63;
    const int rb   = w * 2;               // this wave's 2 rows (in-block)

    float a1[2] = {0.f, 0.f};
    float a2[2] = {0.f, 0.f};
#pragma unroll
    for (int c = 0; c < CC; ++c) {
        const float w1v = w1t[c * PP + lane];
        const float w2v = w2t[c * PP + lane];
        const float x0 = xs[(rb + 0) * CC + c];   // broadcast reads
        const float x1 = xs[(rb + 1) * CC + c];
        a1[0] = fmaf(x0, w1v, a1[0]);  a2[0] = fmaf(x0, w2v, a2[0]);
        a1[1] = fmaf(x1, w1v, a1[1]);  a2[1] = fmaf(x1, w2v, a2[1]);
    }
    const float K2 = 2.8853900817779268f;  // 2*log2(e)
    // e1: natural layout (attn stages a tiny TI x C tile per block)
#pragma unroll
    for (int rr = 0; rr < 2; ++rr) {
        const size_t r = (size_t)(r0 + rb + rr);
        e1p[r * CC + lane] = fast_exp2(fminf(a1[rr] * K2, 15.f));
    }
    // e2: c-quad-major.  float addr = ((b*16 + c/4)*1024 + n)*4 + (c&3).
    {
        const int b  = r0 >> 10;          // batch of this block's rows
        const int n0 = r0 & 1023;         // row index within batch
        const int cq = lane >> 2, cm = lane & 3;
        const size_t base =
            ((((size_t)(b * 16 + cq)) << 10) + (size_t)(n0 + rb)) * 4 + cm;
#pragma unroll
        for (int rr = 0; rr < 2; ++rr) {
            e2p[base + (size_t)rr * 4] = fast_exp2(fminf(a2[rr] * K2, 15.f));
        }
    }
}

// ---------------- Kernel 2: fused att + softmax -----------------------------
// 4-way batched reciprocal for the 4 i's of one (j, c):
//   d_lo = pk_fma(e1lo, e2, 1); d_hi = pk_fma(e1hi, e2, 1)
//   p_lo = d_lo.x*d_lo.y; p_hi = d_hi.x*d_hi.y; r = rcp(p_lo*p_hi)
//   rw = wc*r; t_lo = p_hi*rw (= wc/(d1 d2)); t_hi = p_lo*rw
//   accLo += pk_fma(d_lo.yx, t_lo)  -> accLo.x += wc/d1, accLo.y += wc/d2
//   accHi += pk_fma(d_hi.yx, t_hi)
__device__ __forceinline__ void step4p(v2f e1lo, v2f e1hi, float e2, float wc,
                                       v2f& accLo, v2f& accHi) {
#if __has_builtin(__builtin_elementwise_fma)
    v2f dlo = __builtin_elementwise_fma(e1lo, (v2f){e2, e2}, (v2f){1.f, 1.f});
    v2f dhi = __builtin_elementwise_fma(e1hi, (v2f){e2, e2}, (v2f){1.f, 1.f});
#else
    v2f dlo = e1lo * (v2f){e2, e2} + (v2f){1.f, 1.f};
    v2f dhi = e1hi * (v2f){e2, e2} + (v2f){1.f, 1.f};
#endif
    const float plo = dlo.x * dlo.y;
    const float phi = dhi.x * dhi.y;
    const float r   = fast_rcp(plo * phi);
    const float rw  = wc * r;
    const float tlo = phi * rw;
    const float thi = plo * rw;
    const v2f slo = dlo.yx;               // op_sel half-swap (free in VOP3P)
    const v2f shi = dhi.yx;
#if __has_builtin(__builtin_elementwise_fma)
    accLo = __builtin_elementwise_fma(slo, (v2f){tlo, tlo}, accLo);
    accHi = __builtin_elementwise_fma(shi, (v2f){thi, thi}, accHi);
#else
    accLo = slo * (v2f){tlo, tlo} + accLo;
    accHi = shi * (v2f){thi, thi} + accHi;
#endif
}

__global__ __launch_bounds__(BLK, 2) void attn_kernel(
    const float* __restrict__ e1p, const float* __restrict__ e2p,
    const float* __restrict__ w3, float* __restrict__ out) {
    __shared__ float e1t[CC * TI];          // [c][i] transposed: 1 KB
    __shared__ float att_lds[TI * NN];      // 16 KB

    const int tid = threadIdx.x;            // 0..255
    const int bi  = blockIdx.x;             // 1024 blocks
    const int b   = bi >> 8;                // 256 blocks per batch
    const int i0  = (bi & 255) * TI;

    {   // stage e1 tile transposed: 256 threads cover CC*TI exactly
        const int ii = tid >> 6, c = tid & 63;
        e1t[c * TI + ii] = e1p[(size_t)((b << 10) + i0 + ii) * CC + c];
    }

    // w3: uniform address -> scalar loads; also its sum
    const float4* __restrict__ w3q = (const float4*)w3;
    float sumw3 = 0.f;
#pragma unroll
    for (int q = 0; q < 16; ++q) {
        float4 t = w3q[q];
        sumw3 += (t.x + t.y) + (t.z + t.w);
    }

    __syncthreads();

    const float4* e1t4 = (const float4*)e1t;   // [c] -> 4 i's (broadcast)
    // e2 in c-quad-major layout: float4 (cq, j) at e2b4[cq*1024 + j].
    const float4* __restrict__ e2b4 = ((const float4*)e2p) + ((size_t)b << 14);

    // acc[jj][p]: p=0 -> (i0,i1), p=1 -> (i2,i3); all indices compile-time.
    v2f acc[4][2];
#pragma unroll
    for (int jj = 0; jj < 4; ++jj) {
        acc[jj][0] = (v2f){0.f, 0.f};
        acc[jj][1] = (v2f){0.f, 0.f};
    }

#pragma unroll 1
    for (int ct = 0; ct < 4; ++ct) {               // 4 cq-tiles of 4
#pragma unroll
        for (int q = 0; q < 4; ++q) {
            const int cq = ct * 4 + q;
            float4 L[4];                           // 4 j's, coalesced 1KB/wave
#pragma unroll
            for (int jj = 0; jj < 4; ++jj)
                L[jj] = e2b4[(cq << 10) + tid + (jj << 8)];
            const float4 wv = w3q[cq];             // s_load (uniform)
#pragma unroll
            for (int m = 0; m < 4; ++m) {
                const float4 ev = e1t4[cq * 4 + m]; // ds_read_b128 broadcast
                const v2f e1lo = (v2f){ev.x, ev.y}; // i0,i1 (aligned pair)
                const v2f e1hi = (v2f){ev.z, ev.w}; // i2,i3
                const float wc = (m == 0) ? wv.x : (m == 1) ? wv.y
                               : (m == 2) ? wv.z : wv.w;
#pragma unroll
                for (int jj = 0; jj < 4; ++jj) {
                    const float e2v = (m == 0) ? L[jj].x : (m == 1) ? L[jj].y
                                    : (m == 2) ? L[jj].z : L[jj].w;
                    step4p(e1lo, e1hi, e2v, wc, acc[jj][0], acc[jj][1]);
                }
            }
        }
    }

#pragma unroll
    for (int jj = 0; jj < 4; ++jj) {
        const int j = tid + (jj << 8);
        att_lds[0 * NN + j] = fmaf(-2.f, acc[jj][0].x, sumw3);
        att_lds[1 * NN + j] = fmaf(-2.f, acc[jj][0].y, sumw3);
        att_lds[2 * NN + j] = fmaf(-2.f, acc[jj][1].x, sumw3);
        att_lds[3 * NN + j] = fmaf(-2.f, acc[jj][1].y, sumw3);
    }
    __syncthreads();

    // epilogue: wave w (0..3) softmaxes row i0+w over j — all 4 waves active
    {
        const int w    = tid >> 6;
        const int lane = tid & 63;
        float v[16];
        float m = -3.4e38f;
#pragma unroll
        for (int k = 0; k < 16; ++k) {
            v[k] = att_lds[w * NN + k * 64 + lane];
            m = fmaxf(m, v[k]);
        }
#pragma unroll
        for (int off = 32; off >= 1; off >>= 1)
            m = fmaxf(m, __shfl_xor(m, off));
        const float L2E = 1.4426950408889634f;
        float s = 0.f;
#pragma unroll
        for (int k = 0; k < 16; ++k) {
            v[k] = fast_exp2((v[k] - m) * L2E);
            s += v[k];
        }
#pragma unroll
        for (int off = 32; off >= 1; off >>= 1)
            s += __shfl_xor(s, off);
        const float rs = fast_rcp(s);
        float* __restrict__ orow = out + (((size_t)(b << 10) + (i0 + w)) << 10);
#pragma unroll
        for (int k = 0; k < 16; ++k) orow[k * 64 + lane] = v[k] * rs;
    }
}

extern "C" void kernel_launch(void* const* d_in, const int* in_sizes, int n_in,
                              void* d_out, int out_size, void* d_ws, size_t ws_size,
                              hipStream_t stream) {
    const float* x  = (const float*)d_in[0];
    const float* W1 = (const float*)d_in[1];
    const float* W2 = (const float*)d_in[2];
    const float* w3 = (const float*)d_in[3];
    float* outp = (float*)d_out;

    float* e1p = (float*)d_ws;                       // 4096*64 fp32 = 1 MB (natural)
    float* e2p = e1p + (size_t)BATCH * NN * CC;      // second 1 MB (c-quad-major)

    proj_kernel<<<dim3(BATCH * NN / PROWS), dim3(512), 0, stream>>>(x, W1, W2, e1p, e2p);
    attn_kernel<<<dim3(BATCH * NN / TI), dim3(BLK), 0, stream>>>(e1p, e2p, w3, outp);
}

// Round 11
// 95.512 us; speedup vs baseline: 1.0531x; 1.0531x over previous
//
#include <hip/hip_runtime.h>
#include <hip/hip_bf16.h>

// SpatialAttention: out[b,i,j] = softmax_j( sum_c w3[c] * tanh(x1[b,i,c] + x2[b,j,c]) )
// x1 = x@W1^T, x2 = x@W2^T.  B=4, N=1024, C=64.
//
// tanh(s) = 1 - 2/(exp2(K2*s)+1), K2 = 2*log2(e); exp2 factorizes:
// exp2(K2*(x1+x2)) = e1*e2, precomputed in proj (each clamped to 2^15).
// att = sum(w3) - 2 * sum_c w3[c] * rcp(fma(e1,e2,1)).
// Paired reciprocal over the i-pair: r = rcp(da*db); t = w3c*r;
// acc.x += db*t; acc.y += da*t   (6 full-rate + 1 trans per 2 elements).
//
// R17 (close-out): revert to the session-best measured config (R9, 96.16us).
// Ledger: nine attn-side levers -- e2 coalescing (R7), uniform-SGPR e1 (R10),
// reg double-buffer prefetch (R11), w3-in-LDS (R12), 4-j blocking (R13),
// occupancy shapes (R9/R15), packed fp32 (-25% instr, R14), rcp batching
// (-50% rcp, R16) -- all neutral or negative.  Invariants: occupancy 28-32%,
// VALUBusy 50-60%, attn 40-46us.  Timed window = ~42us harness ws-poison
// fill (fixed) + ~9 proj + ~40 attn + gaps ~= 96us floor for this structure.
// R16's rcp batching cost ~5us (longer dep chain > trans savings) - reverted.

#define BATCH 4
#define NN    1024
#define CC    64
#define TI    4              // rows i per attn block
#define BLK   256
#define PP    65             // padded pitch for transposed W in LDS
#define PROWS 16             // rows per proj block

__device__ __forceinline__ float fast_exp2(float x) {
#if __has_builtin(__builtin_amdgcn_exp2f)
    return __builtin_amdgcn_exp2f(x);
#else
    return exp2f(x);
#endif
}
__device__ __forceinline__ float fast_rcp(float x) {
#if __has_builtin(__builtin_amdgcn_rcpf)
    return __builtin_amdgcn_rcpf(x);
#else
    return 1.0f / x;
#endif
}

// ---------------- Kernel 1: projections -> exp2 factors ---------------------
// grid 256 x 512 thr; block handles rows r0..r0+15; wave w does 2 rows.
// e1p: natural [b*n][c].  e2p: c-quad-major [b][c/4][n][4] (float4 per (cq,n)).
__global__ __launch_bounds__(512) void proj_kernel(
    const float* __restrict__ x, const float* __restrict__ W1,
    const float* __restrict__ W2, float* __restrict__ e1p,
    float* __restrict__ e2p) {
    __shared__ float w1t[CC * PP];        // [c][d] transposed, 16.25 KB
    __shared__ float w2t[CC * PP];
    __shared__ float xs[PROWS * CC];      // [r][c] straight, 4 KB

    const int tid = threadIdx.x;
    const int r0  = blockIdx.x * PROWS;
    {   // W: coalesced load + transpose into LDS
        const float4* __restrict__ W1v = (const float4*)W1;
        const float4* __restrict__ W2v = (const float4*)W2;
#pragma unroll
        for (int k = 0; k < 2; ++k) {
            const int fi = k * 512 + tid;      // float4 index in [0,1024)
            const int r  = fi >> 4;            // row d
            const int c4 = (fi & 15) * 4;      // col c base
            float4 a = W1v[fi], b = W2v[fi];
            w1t[(c4 + 0) * PP + r] = a.x; w1t[(c4 + 1) * PP + r] = a.y;
            w1t[(c4 + 2) * PP + r] = a.z; w1t[(c4 + 3) * PP + r] = a.w;
            w2t[(c4 + 0) * PP + r] = b.x; w2t[(c4 + 1) * PP + r] = b.y;
            w2t[(c4 + 2) * PP + r] = b.z; w2t[(c4 + 3) * PP + r] = b.w;
        }
        // x tile: coalesced, conflict-free
        const int rr = tid >> 6, c = tid & 63;
#pragma unroll
        for (int k = 0; k < 2; ++k) {
            const int r = k * 8 + rr;
            xs[r * CC + c] = x[(size_t)(r0 + r) * CC + c];
        }
    }
    __syncthreads();

    const int w    = tid >> 6;            // 0..7
    const int lane = tid & 63;
    const int rb   = w * 2;               // this wave's 2 rows (in-block)

    float a1[2] = {0.f, 0.f};
    float a2[2] = {0.f, 0.f};
#pragma unroll
    for (int c = 0; c < CC; ++c) {
        const float w1v = w1t[c * PP + lane];
        const float w2v = w2t[c * PP + lane];
        const float x0 = xs[(rb + 0) * CC + c];   // broadcast reads
        const float x1 = xs[(rb + 1) * CC + c];
        a1[0] = fmaf(x0, w1v, a1[0]);  a2[0] = fmaf(x0, w2v, a2[0]);
        a1[1] = fmaf(x1, w1v, a1[1]);  a2[1] = fmaf(x1, w2v, a2[1]);
    }
    const float K2 = 2.8853900817779268f;  // 2*log2(e)
    // e1: natural layout (attn stages a tiny TI x C tile per block)
#pragma unroll
    for (int rr = 0; rr < 2; ++rr) {
        const size_t r = (size_t)(r0 + rb + rr);
        e1p[r * CC + lane] = fast_exp2(fminf(a1[rr] * K2, 15.f));
    }
    // e2: c-quad-major.  float addr = ((b*16 + c/4)*1024 + n)*4 + (c&3).
    {
        const int b  = r0 >> 10;          // batch of this block's rows
        const int n0 = r0 & 1023;         // row index within batch
        const int cq = lane >> 2, cm = lane & 3;
        const size_t base =
            ((((size_t)(b * 16 + cq)) << 10) + (size_t)(n0 + rb)) * 4 + cm;
#pragma unroll
        for (int rr = 0; rr < 2; ++rr) {
            e2p[base + (size_t)rr * 4] = fast_exp2(fminf(a2[rr] * K2, 15.f));
        }
    }
}

// ---------------- Kernel 2: fused att + softmax -----------------------------
// paired reciprocal for one i-pair, one j (2 elements):
__device__ __forceinline__ void step2(float e1a, float e1b, float e2,
                                      float wc, float2& acc) {
    float da = fmaf(e1a, e2, 1.f);
    float db = fmaf(e1b, e2, 1.f);
    float r  = fast_rcp(da * db);
    float t  = wc * r;
    acc.x = fmaf(db, t, acc.x);   // w3c / da
    acc.y = fmaf(da, t, acc.y);   // w3c / db
}

__global__ __launch_bounds__(BLK) void attn_kernel(
    const float* __restrict__ e1p, const float* __restrict__ e2p,
    const float* __restrict__ w3, float* __restrict__ out) {
    __shared__ float e1t[CC * TI];          // [c][i] transposed: 1 KB
    __shared__ float att_lds[TI * NN];      // 16 KB

    const int tid = threadIdx.x;            // 0..255
    const int bi  = blockIdx.x;             // 1024 blocks
    const int b   = bi >> 8;                // 256 blocks per batch
    const int i0  = (bi & 255) * TI;

    {   // stage e1 tile transposed: 256 threads cover CC*TI exactly
        const int ii = tid >> 6, c = tid & 63;
        e1t[c * TI + ii] = e1p[(size_t)((b << 10) + i0 + ii) * CC + c];
    }
    __syncthreads();

    // w3: uniform address -> scalar loads; also its sum
    const float4* __restrict__ w3q = (const float4*)w3;
    float sumw3 = 0.f;
#pragma unroll
    for (int q = 0; q < 16; ++q) {
        float4 t = w3q[q];
        sumw3 += (t.x + t.y) + (t.z + t.w);
    }

    // e2 in c-quad-major layout: float4 (cq, j) at e2b4[cq*1024 + j].
    const float4* __restrict__ e2b4 = ((const float4*)e2p) + ((size_t)b << 14);
    const float4* e1t4 = (const float4*)e1t;   // [c] -> 4 i's (broadcast)

#pragma unroll 1
    for (int ch = 0; ch < 2; ++ch) {
        const int jA = (ch << 8) + tid;     // 0..511
        const int jB = jA + 512;            // 512..1023

        float2 accA1 = {0.f, 0.f}, accB1 = {0.f, 0.f};   // jA: (i0,i1),(i2,i3)
        float2 accA2 = {0.f, 0.f}, accB2 = {0.f, 0.f};   // jB

#pragma unroll 1
        for (int ct = 0; ct < 4; ++ct) {               // 4 cq-tiles of 4
            // hoist 8 independent VMEM loads for this ct
            float4 La[4], Lb[4];
#pragma unroll
            for (int q = 0; q < 4; ++q) {
                const int cq = ct * 4 + q;
                La[q] = e2b4[(cq << 10) + jA];
                Lb[q] = e2b4[(cq << 10) + jB];
            }
#pragma unroll
            for (int q = 0; q < 4; ++q) {
                const int cq = ct * 4 + q;
                const float4 wv  = w3q[cq];            // s_load (uniform)
                const float eA[4] = {La[q].x, La[q].y, La[q].z, La[q].w};
                const float eB[4] = {Lb[q].x, Lb[q].y, Lb[q].z, Lb[q].w};
                const float wa[4] = {wv.x, wv.y, wv.z, wv.w};
#pragma unroll
                for (int m = 0; m < 4; ++m) {
                    const int c = cq * 4 + m;
                    const float4 ev = e1t4[c];         // LDS broadcast b128
                    step2(ev.x, ev.y, eA[m], wa[m], accA1);
                    step2(ev.z, ev.w, eA[m], wa[m], accB1);
                    step2(ev.x, ev.y, eB[m], wa[m], accA2);
                    step2(ev.z, ev.w, eB[m], wa[m], accB2);
                }
            }
        }
        att_lds[0 * NN + jA] = fmaf(-2.f, accA1.x, sumw3);
        att_lds[1 * NN + jA] = fmaf(-2.f, accA1.y, sumw3);
        att_lds[2 * NN + jA] = fmaf(-2.f, accB1.x, sumw3);
        att_lds[3 * NN + jA] = fmaf(-2.f, accB1.y, sumw3);
        att_lds[0 * NN + jB] = fmaf(-2.f, accA2.x, sumw3);
        att_lds[1 * NN + jB] = fmaf(-2.f, accA2.y, sumw3);
        att_lds[2 * NN + jB] = fmaf(-2.f, accB2.x, sumw3);
        att_lds[3 * NN + jB] = fmaf(-2.f, accB2.y, sumw3);
    }
    __syncthreads();

    // epilogue: wave w (0..3) softmaxes row i0+w over j — all 4 waves active
    {
        const int w    = tid >> 6;
        const int lane = tid & 63;
        float v[16];
        float m = -3.4e38f;
#pragma unroll
        for (int k = 0; k < 16; ++k) {
            v[k] = att_lds[w * NN + k * 64 + lane];
            m = fmaxf(m, v[k]);
        }
#pragma unroll
        for (int off = 32; off >= 1; off >>= 1)
            m = fmaxf(m, __shfl_xor(m, off));
        const float L2E = 1.4426950408889634f;
        float s = 0.f;
#pragma unroll
        for (int k = 0; k < 16; ++k) {
            v[k] = fast_exp2((v[k] - m) * L2E);
            s += v[k];
        }
#pragma unroll
        for (int off = 32; off >= 1; off >>= 1)
            s += __shfl_xor(s, off);
        const float rs = fast_rcp(s);
        float* __restrict__ orow = out + (((size_t)(b << 10) + (i0 + w)) << 10);
#pragma unroll
        for (int k = 0; k < 16; ++k) orow[k * 64 + lane] = v[k] * rs;
    }
}

extern "C" void kernel_launch(void* const* d_in, const int* in_sizes, int n_in,
                              void* d_out, int out_size, void* d_ws, size_t ws_size,
                              hipStream_t stream) {
    const float* x  = (const float*)d_in[0];
    const float* W1 = (const float*)d_in[1];
    const float* W2 = (const float*)d_in[2];
    const float* w3 = (const float*)d_in[3];
    float* outp = (float*)d_out;

    float* e1p = (float*)d_ws;                       // 4096*64 fp32 = 1 MB (natural)
    float* e2p = e1p + (size_t)BATCH * NN * CC;      // second 1 MB (c-quad-major)

    proj_kernel<<<dim3(BATCH * NN / PROWS), dim3(512), 0, stream>>>(x, W1, W2, e1p, e2p);
    attn_kernel<<<dim3(BATCH * NN / TI), dim3(BLK), 0, stream>>>(e1p, e2p, w3, outp);
}